// Round 16
// baseline (628.847 us; speedup 1.0000x reference)
//
#include <hip/hip_runtime.h>
#include <hip/hip_bf16.h>

#define D_ 128

typedef __attribute__((ext_vector_type(8))) short s8b;   // 8 bf16
typedef __attribute__((ext_vector_type(4))) float f4;    // MFMA acc

union U4 { uint u[4]; s8b v; uint4 q; };

// async global->LDS, 16B per lane, dest = uniform base + lane*16 (linear)
__device__ __forceinline__ void gl16(const void* g, void* lds) {
    __builtin_amdgcn_global_load_lds(
        (const __attribute__((address_space(1))) void*)g,
        (__attribute__((address_space(3))) void*)lds, 16, 0, 0);
}

// split two fp32 into packed bf16 high (truncate) + low (RNE of residual)
__device__ __forceinline__ void split2(float f0, float f1, uint& hp, uint& lp) {
    uint u0 = __float_as_uint(f0), u1 = __float_as_uint(f1);
    hp = (u0 >> 16) | (u1 & 0xffff0000u);
    float r0 = f0 - __uint_as_float(u0 & 0xffff0000u);
    float r1 = f1 - __uint_as_float(u1 & 0xffff0000u);
    uint v0 = __float_as_uint(r0), v1 = __float_as_uint(r1);
    uint l0 = (v0 + 0x7fffu + ((v0 >> 16) & 1u)) >> 16;
    uint l1 = (v1 + 0x7fffu + ((v1 >> 16) & 1u)) >> 16;
    lp = l0 | (l1 << 16);
}

__device__ __forceinline__ float4 asf4(uint4 u) {
    return make_float4(__uint_as_float(u.x), __uint_as_float(u.y),
                       __uint_as_float(u.z), __uint_as_float(u.w));
}

// ---------------- degree (both relations) ----------------
__global__ void deg2_kernel(const int* __restrict__ dstA, const int* __restrict__ dstB,
                            int* __restrict__ degA, int* __restrict__ degB, int E) {
    int e = blockIdx.x * blockDim.x + threadIdx.x;
    const int* dst = blockIdx.y ? dstB : dstA;
    int* deg = blockIdx.y ? degB : degA;
    if (e < E) atomicAdd(&deg[dst[e]], 1);
}

// ---------------- exclusive scan (3-kernel, both relations) ----------------
__global__ __launch_bounds__(256)
void scan1m(const int* __restrict__ degA, const int* __restrict__ degB,
            int* __restrict__ rpA, int* __restrict__ rpB,
            int* __restrict__ partA, int* __restrict__ partB, int N) {
    const int* deg = blockIdx.y ? degB : degA;
    int* rp = blockIdx.y ? rpB : rpA;
    int* partials = blockIdx.y ? partB : partA;
    int tid = threadIdx.x;
    int i = blockIdx.x * 256 + tid;
    int v = (i < N) ? deg[i] : 0;
    int lane = tid & 63, wid = tid >> 6;
    int x = v;
#pragma unroll
    for (int off = 1; off < 64; off <<= 1) {
        int y = __shfl_up(x, off, 64);
        if (lane >= off) x += y;
    }
    __shared__ int wsum[5];
    if (lane == 63) wsum[wid] = x;
    __syncthreads();
    if (tid == 0) {
        int a = wsum[0], b = wsum[1], c = wsum[2], d = wsum[3];
        wsum[0] = 0; wsum[1] = a; wsum[2] = a + b; wsum[3] = a + b + c;
        wsum[4] = a + b + c + d;
    }
    __syncthreads();
    if (i < N) rp[i] = wsum[wid] + x - v;
    if (tid == 0) partials[blockIdx.x] = wsum[4];
}

__global__ __launch_bounds__(1024)
void scan2m(int* __restrict__ partA, int* __restrict__ partB, int B) {
    int* partials = blockIdx.x ? partB : partA;
    __shared__ int buf[1024];
    int t = threadIdx.x;
    int v = (t < B) ? partials[t] : 0;
    buf[t] = v;
    __syncthreads();
    for (int off = 1; off < 1024; off <<= 1) {
        int add = (t >= off) ? buf[t - off] : 0;
        __syncthreads();
        buf[t] += add;
        __syncthreads();
    }
    if (t < B) partials[t] = buf[t] - v;
}

__global__ __launch_bounds__(256)
void scan3m(int* __restrict__ rpA, int* __restrict__ rpB,
            const int* __restrict__ partA, const int* __restrict__ partB, int N, int E) {
    int* rp = blockIdx.y ? rpB : rpA;
    const int* partials = blockIdx.y ? partB : partA;
    int i = blockIdx.x * 256 + threadIdx.x;
    if (i < N) rp[i] += partials[blockIdx.x];
    if (i == 0) rp[N] = E;
}

// ---------------- CSR fill (both relations) + first-4 pack ----------------
__global__ void fill2_csr(const int* __restrict__ srcA, const int* __restrict__ dstA,
                          const int* __restrict__ rpA, int* __restrict__ curA,
                          int* __restrict__ colA, int* __restrict__ colpA,
                          const int* __restrict__ srcB, const int* __restrict__ dstB,
                          const int* __restrict__ rpB, int* __restrict__ curB,
                          int* __restrict__ colB, int* __restrict__ colpB, int E) {
    int e = blockIdx.x * blockDim.x + threadIdx.x;
    if (e >= E) return;
    const int* src = blockIdx.y ? srcB : srcA;
    const int* dst = blockIdx.y ? dstB : dstA;
    const int* rp  = blockIdx.y ? rpB : rpA;
    int* cursor = blockIdx.y ? curB : curA;
    int* col    = blockIdx.y ? colB : colA;
    int* colp   = blockIdx.y ? colpB : colpA;
    int d = dst[e];
    int s = src[e];
    int idx = atomicAdd(&cursor[d], 1);
    col[rp[d] + idx] = s;
    if (idx < 4) colp[d * 4 + idx] = s;
}

// ---------------- weight prep: transpose + bf16 h/l split ----------------
// WT layout per config g: [col 0..127][kv 0..255] (kv<128 self, >=128 neigh)
__global__ __launch_bounds__(256)
void prep_weights(const float* __restrict__ s0, const float* __restrict__ n0,
                  const float* __restrict__ s1, const float* __restrict__ n1,
                  const float* __restrict__ s2, const float* __restrict__ n2,
                  const float* __restrict__ s3, const float* __restrict__ n3,
                  ushort* __restrict__ WTH, ushort* __restrict__ WTL) {
    int g = blockIdx.y;
    int t = blockIdx.x * 256 + threadIdx.x;   // 0..4095
    int c = t & 127;
    int oct = t >> 7;                          // 0..31 (8 kv each)
    const float* self  = g == 0 ? s0 : g == 1 ? s1 : g == 2 ? s2 : s3;
    const float* neigh = g == 0 ? n0 : g == 1 ? n1 : g == 2 ? n2 : n3;
    uint hd[4], ld_[4];
#pragma unroll
    for (int p = 0; p < 4; ++p) {
        uint hpair = 0, lpair = 0;
#pragma unroll
        for (int q = 0; q < 2; ++q) {
            int kv = oct * 8 + p * 2 + q;
            const float* Wsrc = kv < 128 ? self : neigh;
            float f = Wsrc[(size_t)(kv & 127) * 128 + c];
            uint u = __float_as_uint(f);
            uint h = u >> 16;
            float r = f - __uint_as_float(u & 0xffff0000u);
            uint v = __float_as_uint(r);
            uint l = (v + 0x7fffu + ((v >> 16) & 1u)) >> 16;
            hpair |= h << (16 * q);
            lpair |= l << (16 * q);
        }
        hd[p] = hpair; ld_[p] = lpair;
    }
    size_t base = ((size_t)g * 128 + c) * 256 + oct * 8;
    *(uint4*)(WTH + base) = make_uint4(hd[0], hd[1], hd[2], hd[3]);
    *(uint4*)(WTL + base) = make_uint4(ld_[0], ld_[1], ld_[2], ld_[3]);
}

// ---------------- FUSED gather-mean + dual GEMM: 32-row tiles, 256 threads ----------------
// 4 waves of 32x32; 4 blocks/CU (36KB LDS) for block-level phase diversity.
// K-loop: ks 0-3 A1 streamed, ks 4-7 agg RESIDENT in LDS.
// LDS: AggH[0,8K) AggL[8K,16K) Astep[16K,20K) Wh[20K,28K) Wl[28K,36K).
#define AGGH 0
#define AGGL 8192
#define ASTEP 16384
#define WHO 20480
#define WLO 28672

template<int FP32IN, int SPLIT, int LRELU>
__device__ __forceinline__ void fused_body(const char* A1, const char* XN,
        const int* rp, const int* col, const int* colp,
        const ushort* WTh, const ushort* WTl, const float* bias, void* outp,
        int bid, char* smem) {
    const int t = threadIdx.x;
    const int row0 = bid * 32;
    const int li = t & 15;

    // ---- gather phase: 32 nodes, 16 lanes/node, 2 passes
#pragma unroll
    for (int p = 0; p < 2; ++p) {
        int nl = p * 16 + (t >> 4);            // 0..31
        int node = row0 + nl;
        int beg = rp[node], end = rp[node + 1];
        int dg = end - beg;
        int4 c4 = *(const int4*)(colp + (size_t)node * 4);
        int s0 = dg > 0 ? c4.x : 0;
        int s1 = dg > 1 ? c4.y : 0;
        int s2 = dg > 2 ? c4.z : 0;
        int s3 = dg > 3 ? c4.w : 0;
        float w0 = dg > 0 ? 1.f : 0.f;
        float w1 = dg > 1 ? 1.f : 0.f;
        float w2 = dg > 2 ? 1.f : 0.f;
        float w3 = dg > 3 ? 1.f : 0.f;
        float a[8];
#pragma unroll
        for (int j = 0; j < 8; ++j) a[j] = 0.f;
        const int lo = FP32IN ? li * 32 : li * 16;
        const int d2 = FP32IN ? 16 : 256;
        const char* p0 = XN + (size_t)s0 * 512 + lo;
        const char* p1 = XN + (size_t)s1 * 512 + lo;
        const char* p2 = XN + (size_t)s2 * 512 + lo;
        const char* p3 = XN + (size_t)s3 * 512 + lo;
        uint4 H0 = *(const uint4*)p0, L0 = *(const uint4*)(p0 + d2);
        uint4 H1 = *(const uint4*)p1, L1 = *(const uint4*)(p1 + d2);
        uint4 H2 = *(const uint4*)p2, L2 = *(const uint4*)(p2 + d2);
        uint4 H3 = *(const uint4*)p3, L3 = *(const uint4*)(p3 + d2);
        if (FP32IN) {
#pragma unroll
            for (int q = 0; q < 4; ++q) {
                uint4 Hq = q == 0 ? H0 : q == 1 ? H1 : q == 2 ? H2 : H3;
                uint4 Lq = q == 0 ? L0 : q == 1 ? L1 : q == 2 ? L2 : L3;
                float wq = q == 0 ? w0 : q == 1 ? w1 : q == 2 ? w2 : w3;
                float4 X = asf4(Hq), Y = asf4(Lq);
                a[0] = fmaf(X.x, wq, a[0]); a[1] = fmaf(X.y, wq, a[1]);
                a[2] = fmaf(X.z, wq, a[2]); a[3] = fmaf(X.w, wq, a[3]);
                a[4] = fmaf(Y.x, wq, a[4]); a[5] = fmaf(Y.y, wq, a[5]);
                a[6] = fmaf(Y.z, wq, a[6]); a[7] = fmaf(Y.w, wq, a[7]);
            }
            for (int e = beg + 4; e < end; ++e) {
                const char* pp = XN + (size_t)col[e] * 512 + li * 32;
                float4 X = *(const float4*)pp, Y = *(const float4*)(pp + 16);
                a[0] += X.x; a[1] += X.y; a[2] += X.z; a[3] += X.w;
                a[4] += Y.x; a[5] += Y.y; a[6] += Y.z; a[7] += Y.w;
            }
        } else {
#pragma unroll
            for (int q = 0; q < 4; ++q) {
                uint4 Hq = q == 0 ? H0 : q == 1 ? H1 : q == 2 ? H2 : H3;
                uint4 Lq = q == 0 ? L0 : q == 1 ? L1 : q == 2 ? L2 : L3;
                float wq = q == 0 ? w0 : q == 1 ? w1 : q == 2 ? w2 : w3;
                const ushort* hu = (const ushort*)&Hq;
                const ushort* lu = (const ushort*)&Lq;
#pragma unroll
                for (int j = 0; j < 8; ++j) {
                    float v = __uint_as_float((uint)hu[j] << 16)
                            + __uint_as_float((uint)lu[j] << 16);
                    a[j] = fmaf(v, wq, a[j]);
                }
            }
            for (int e = beg + 4; e < end; ++e) {
                const char* pp = XN + (size_t)col[e] * 512 + li * 16;
                uint4 H = *(const uint4*)pp, L = *(const uint4*)(pp + 256);
                const ushort* hu = (const ushort*)&H;
                const ushort* lu = (const ushort*)&L;
#pragma unroll
                for (int j = 0; j < 8; ++j)
                    a[j] += __uint_as_float((uint)hu[j] << 16)
                          + __uint_as_float((uint)lu[j] << 16);
            }
        }
        float inv = 1.f / (float)(dg > 0 ? dg : 1);
        uint h[4], l[4];
        split2(a[0] * inv, a[1] * inv, h[0], l[0]);
        split2(a[2] * inv, a[3] * inv, h[1], l[1]);
        split2(a[4] * inv, a[5] * inv, h[2], l[2]);
        split2(a[6] * inv, a[7] * inv, h[3], l[3]);
        int chunk = li ^ (nl & 3) ^ (((nl >> 2) & 3) << 2);   // involution
        *(uint4*)(smem + AGGH + nl * 256 + chunk * 16) = make_uint4(h[0], h[1], h[2], h[3]);
        *(uint4*)(smem + AGGL + nl * 256 + chunk * 16) = make_uint4(l[0], l[1], l[2], l[3]);
    }

    // ---- MFMA setup: 4 waves, each 32 rows x 32 cols
    const int w = t >> 6, lane = t & 63;
    const int fr = lane & 15, hi = lane >> 4;
    const int ncol0 = w * 32;

    f4 acc[2][2];
    {
        float bv[2];
#pragma unroll
        for (int n = 0; n < 2; ++n) bv[n] = bias[ncol0 + n * 16 + fr];
#pragma unroll
        for (int m = 0; m < 2; ++m)
#pragma unroll
            for (int n = 0; n < 2; ++n) acc[m][n] = (f4){bv[n], bv[n], bv[n], bv[n]};
    }

    auto stage = [&](int ks) {
        if (ks < 4) {
            if (FP32IN) {
                int row = t >> 3, cs = t & 7;                 // 32 rows x 8 chunks
                gl16(A1 + (size_t)(row0 + row) * 512 + ks * 128 + ((cs ^ (row & 7)) * 16),
                     smem + ASTEP + t * 16);
            } else {
                int j = t & 127, part = t >> 7;               // 32 rows x 4 chunks, h/l
                int row = j >> 2, cs = j & 3;
                gl16(A1 + (size_t)(row0 + row) * 512 + part * 256 + ks * 64
                         + ((cs ^ ((row >> 1) & 3)) * 16),
                     smem + ASTEP + part * 2048 + j * 16);
            }
        }
#pragma unroll
        for (int it = 0; it < 2; ++it) {
            int j = it * 256 + t;                             // 0..511: 128 cols x 4 chunks
            int col_ = j >> 2, cs = j & 3;
            size_t so = (size_t)col_ * 512 + ks * 64 + ((cs ^ ((col_ >> 1) & 3)) * 16);
            gl16((const char*)WTh + so, smem + WHO + j * 16);
            gl16((const char*)WTl + so, smem + WLO + j * 16);
        }
    };

    auto compute = [&](int ks) {
        s8b ah[2], al[2], wh[2], wl[2];
        if (ks < 4) {
            if (FP32IN) {
#pragma unroll
                for (int m = 0; m < 2; ++m) {
                    int r = m * 16 + fr;
                    f4 x0 = *(const f4*)(smem + ASTEP + r * 128 + (((hi * 2) ^ (r & 7)) * 16));
                    f4 x1 = *(const f4*)(smem + ASTEP + r * 128 + (((hi * 2 + 1) ^ (r & 7)) * 16));
                    U4 H, L;
                    split2(x0[0], x0[1], H.u[0], L.u[0]);
                    split2(x0[2], x0[3], H.u[1], L.u[1]);
                    split2(x1[0], x1[1], H.u[2], L.u[2]);
                    split2(x1[2], x1[3], H.u[3], L.u[3]);
                    ah[m] = H.v; al[m] = L.v;
                }
            } else {
#pragma unroll
                for (int m = 0; m < 2; ++m) {
                    int r = m * 16 + fr;
                    int off = r * 64 + ((hi ^ ((r >> 1) & 3)) * 16);
                    ah[m] = *(const s8b*)(smem + ASTEP + off);
                    al[m] = *(const s8b*)(smem + ASTEP + 2048 + off);
                }
            }
        } else {
            int kk = ks - 4;
#pragma unroll
            for (int m = 0; m < 2; ++m) {
                int r = m * 16 + fr;
                int chunk = (kk * 4 + hi) ^ (r & 3) ^ (((r >> 2) & 3) << 2);
                ah[m] = *(const s8b*)(smem + AGGH + r * 256 + chunk * 16);
                al[m] = *(const s8b*)(smem + AGGL + r * 256 + chunk * 16);
            }
        }
#pragma unroll
        for (int n = 0; n < 2; ++n) {
            int c = ncol0 + n * 16 + fr;
            int off = c * 64 + ((hi ^ ((c >> 1) & 3)) * 16);
            wh[n] = *(const s8b*)(smem + WHO + off);
            wl[n] = *(const s8b*)(smem + WLO + off);
        }
#pragma unroll
        for (int n = 0; n < 2; ++n)
#pragma unroll
            for (int m = 0; m < 2; ++m) {
                acc[m][n] = __builtin_amdgcn_mfma_f32_16x16x32_bf16(ah[m], wh[n], acc[m][n], 0, 0, 0);
                acc[m][n] = __builtin_amdgcn_mfma_f32_16x16x32_bf16(al[m], wh[n], acc[m][n], 0, 0, 0);
                acc[m][n] = __builtin_amdgcn_mfma_f32_16x16x32_bf16(ah[m], wl[n], acc[m][n], 0, 0, 0);
            }
    };

    // ---- K-loop (Agg writes ordered before ks4 reads by the intervening barriers)
    for (int ks = 0; ks < 8; ++ks) {
        stage(ks);
        __syncthreads();
        compute(ks);
        __syncthreads();
    }

    // ---- epilogue: LDS transpose (32 x 132 fp32 = 16.9KB, reuses Agg region)
    float* T = (float*)smem;
#pragma unroll
    for (int m = 0; m < 2; ++m)
#pragma unroll
        for (int n = 0; n < 2; ++n)
#pragma unroll
            for (int r = 0; r < 4; ++r)
                T[(m * 16 + hi * 4 + r) * 132 + ncol0 + n * 16 + fr] = acc[m][n][r];
    __syncthreads();
    {
        int row = t >> 3, q = t & 7;            // 8 lanes per row
        int gr = row0 + row;
        if (SPLIT) {
            char* ob = (char*)outp + (size_t)gr * 512;
#pragma unroll
            for (int i = 0; i < 2; ++i) {
                const float* p = T + row * 132 + (q * 2 + i) * 8;
                f4 x0 = *(const f4*)p;
                f4 x1 = *(const f4*)(p + 4);
                float e[8] = {x0[0], x0[1], x0[2], x0[3], x1[0], x1[1], x1[2], x1[3]};
                if (LRELU) {
#pragma unroll
                    for (int j = 0; j < 8; ++j) e[j] = e[j] > 0.f ? e[j] : 0.01f * e[j];
                }
                uint h[4], l[4];
#pragma unroll
                for (int j = 0; j < 4; ++j) split2(e[2 * j], e[2 * j + 1], h[j], l[j]);
                *(uint4*)(ob + (q * 2 + i) * 16) = make_uint4(h[0], h[1], h[2], h[3]);
                *(uint4*)(ob + 256 + (q * 2 + i) * 16) = make_uint4(l[0], l[1], l[2], l[3]);
            }
        } else {
            float* ob = (float*)outp + (size_t)gr * 128;
#pragma unroll
            for (int i = 0; i < 4; ++i) {
                f4 x = *(const f4*)(T + row * 132 + q * 16 + i * 4);
                float e0 = x[0], e1 = x[1], e2 = x[2], e3 = x[3];
                if (LRELU) {
                    e0 = e0 > 0.f ? e0 : 0.01f * e0;
                    e1 = e1 > 0.f ? e1 : 0.01f * e1;
                    e2 = e2 > 0.f ? e2 : 0.01f * e2;
                    e3 = e3 > 0.f ? e3 : 0.01f * e3;
                }
                *(float4*)(ob + q * 16 + i * 4) = make_float4(e0, e1, e2, e3);
            }
        }
    }
}

template<int FP32IN, int SPLIT, int LRELU>
__global__ __launch_bounds__(256, 4)
void fused2k(const void* A1a, const void* XNa, const int* rpA, const int* colA,
             const int* colpA, const ushort* WTha, const ushort* WTla,
             const float* ba, void* outa,
             const void* A1b, const void* XNb, const int* rpB, const int* colB,
             const int* colpB, const ushort* WThb, const ushort* WTlb,
             const float* bb, void* outb, int blocksA) {
    __shared__ __align__(16) char smem[36864];
    bool isA = (int)blockIdx.x < blocksA;
    int bid = isA ? blockIdx.x : blockIdx.x - blocksA;
    if (isA)
        fused_body<FP32IN, SPLIT, LRELU>((const char*)A1a, (const char*)XNa, rpA, colA,
                                         colpA, WTha, WTla, ba, outa, bid, smem);
    else
        fused_body<FP32IN, SPLIT, LRELU>((const char*)A1b, (const char*)XNb, rpB, colB,
                                         colpB, WThb, WTlb, bb, outb, bid, smem);
}

extern "C" void kernel_launch(void* const* d_in, const int* in_sizes, int n_in,
                              void* d_out, int out_size, void* d_ws, size_t ws_size,
                              hipStream_t stream) {
    const float* x_user     = (const float*)d_in[0];
    const float* x_item     = (const float*)d_in[1];
    const float* w1_self_uc = (const float*)d_in[2];
    const float* w1_neigh_uc= (const float*)d_in[3];
    const float* b1_uc      = (const float*)d_in[4];
    const float* w1_self_iu = (const float*)d_in[5];
    const float* w1_neigh_iu= (const float*)d_in[6];
    const float* b1_iu      = (const float*)d_in[7];
    const float* w2_self_uc = (const float*)d_in[8];
    const float* w2_neigh_uc= (const float*)d_in[9];
    const float* b2_uc      = (const float*)d_in[10];
    const float* w2_self_iu = (const float*)d_in[11];
    const float* w2_neigh_iu= (const float*)d_in[12];
    const float* b2_iu      = (const float*)d_in[13];
    const int* src_uc = (const int*)d_in[14];
    const int* dst_uc = (const int*)d_in[15];
    const int* src_iu = (const int*)d_in[16];
    const int* dst_iu = (const int*)d_in[17];

    const int NU = in_sizes[0] / D_;
    const int NI = in_sizes[1] / D_;
    const int E  = in_sizes[14];

    float* f_user = (float*)d_out;
    float* f_item = (float*)d_out + (size_t)NU * 128;

    // workspace layout: h1 (hl form) lives in ws; d_out written only by layer 2
    char* ws = (char*)d_ws;
    const size_t FEAT_BYTES = (size_t)200000 * 512;      // 102.4 MB (hl rows)
    char* h1_item  = ws;          ws += FEAT_BYTES;
    char* h1_user  = ws;          ws += FEAT_BYTES;
    ushort* WTH    = (ushort*)ws; ws += (size_t)4 * 128 * 256 * sizeof(ushort);
    ushort* WTL    = (ushort*)ws; ws += (size_t)4 * 128 * 256 * sizeof(ushort);
    int* colp_uc   = (int*)ws;    ws += (size_t)200000 * 4 * sizeof(int);
    int* colp_iu   = (int*)ws;    ws += (size_t)200000 * 4 * sizeof(int);
    int* rp_uc     = (int*)ws;    ws += (size_t)(NI + 1) * sizeof(int);
    int* rp_iu     = (int*)ws;    ws += (size_t)(NU + 1) * sizeof(int);
    int* col_uc    = (int*)ws;    ws += (size_t)E * sizeof(int);
    int* col_iu    = (int*)ws;    ws += (size_t)E * sizeof(int);
    int* deg_uc    = (int*)ws;    ws += (size_t)200000 * sizeof(int);
    int* deg_iu    = (int*)ws;    ws += (size_t)200000 * sizeof(int);
    int* cur_uc    = (int*)ws;    ws += (size_t)200000 * sizeof(int);
    int* cur_iu    = (int*)ws;    ws += (size_t)200000 * sizeof(int);
    int* partA     = (int*)ws;    ws += (size_t)1024 * sizeof(int);
    int* partB     = (int*)ws;    ws += (size_t)1024 * sizeof(int);

    const int TPB = 256;
    const int eBlocks  = (E + TPB - 1) / TPB;
    const int sBlocks  = (200000 + 255) / 256;
    const int mBlocksI = (NI + 31) / 32;
    const int mBlocksU = (NU + 31) / 32;
    const size_t WSTRIDE = (size_t)128 * 256;  // g0=l1_uc g1=l1_iu g2=l2_uc g3=l2_iu

    hipMemsetAsync(deg_uc, 0, (size_t)4 * 200000 * sizeof(int), stream); // deg+cursor both rel

    prep_weights<<<dim3(16, 4), 256, 0, stream>>>(
        w1_self_uc, w1_neigh_uc, w1_self_iu, w1_neigh_iu,
        w2_self_uc, w2_neigh_uc, w2_self_iu, w2_neigh_iu, WTH, WTL);

    deg2_kernel<<<dim3(eBlocks, 2), TPB, 0, stream>>>(dst_uc, dst_iu, deg_uc, deg_iu, E);
    scan1m<<<dim3(sBlocks, 2), 256, 0, stream>>>(deg_uc, deg_iu, rp_uc, rp_iu, partA, partB, 200000);
    scan2m<<<2, 1024, 0, stream>>>(partA, partB, sBlocks);
    scan3m<<<dim3(sBlocks, 2), 256, 0, stream>>>(rp_uc, rp_iu, partA, partB, 200000, E);
    fill2_csr<<<dim3(eBlocks, 2), TPB, 0, stream>>>(src_uc, dst_uc, rp_uc, cur_uc, col_uc, colp_uc,
                                                    src_iu, dst_iu, rp_iu, cur_iu, col_iu, colp_iu, E);

    // ---- layer 1 (fused): item side gathers x_user via uc-CSR; user side gathers x_item
    fused2k<1, 1, 1><<<mBlocksI + mBlocksU, 256, 0, stream>>>(
        x_item, x_user, rp_uc, col_uc, colp_uc, WTH + 0 * WSTRIDE, WTL + 0 * WSTRIDE,
        b1_uc, h1_item,
        x_user, x_item, rp_iu, col_iu, colp_iu, WTH + 1 * WSTRIDE, WTL + 1 * WSTRIDE,
        b1_iu, h1_user, mBlocksI);

    // ---- layer 2 (fused): reads h1 from ws, writes fp32 d_out (no aliasing)
    fused2k<0, 0, 0><<<mBlocksI + mBlocksU, 256, 0, stream>>>(
        h1_item, h1_user, rp_uc, col_uc, colp_uc, WTH + 2 * WSTRIDE, WTL + 2 * WSTRIDE,
        b2_uc, f_item,
        h1_user, h1_item, rp_iu, col_iu, colp_iu, WTH + 3 * WSTRIDE, WTL + 3 * WSTRIDE,
        b2_iu, f_user, mBlocksI);
}

// Round 17
// 528.636 us; speedup vs baseline: 1.1896x; 1.1896x over previous
//
#include <hip/hip_runtime.h>
#include <hip/hip_bf16.h>

#define D_ 128

typedef __attribute__((ext_vector_type(8))) short s8b;   // 8 bf16
typedef __attribute__((ext_vector_type(4))) float f4;    // MFMA acc

union U4 { uint u[4]; s8b v; uint4 q; };

// async global->LDS, 16B per lane, dest = uniform base + lane*16 (linear)
__device__ __forceinline__ void gl16(const void* g, void* lds) {
    __builtin_amdgcn_global_load_lds(
        (const __attribute__((address_space(1))) void*)g,
        (__attribute__((address_space(3))) void*)lds, 16, 0, 0);
}

// split two fp32 into packed bf16 high (truncate) + low (RNE of residual)
__device__ __forceinline__ void split2(float f0, float f1, uint& hp, uint& lp) {
    uint u0 = __float_as_uint(f0), u1 = __float_as_uint(f1);
    hp = (u0 >> 16) | (u1 & 0xffff0000u);
    float r0 = f0 - __uint_as_float(u0 & 0xffff0000u);
    float r1 = f1 - __uint_as_float(u1 & 0xffff0000u);
    uint v0 = __float_as_uint(r0), v1 = __float_as_uint(r1);
    uint l0 = (v0 + 0x7fffu + ((v0 >> 16) & 1u)) >> 16;
    uint l1 = (v1 + 0x7fffu + ((v1 >> 16) & 1u)) >> 16;
    lp = l0 | (l1 << 16);
}

__device__ __forceinline__ float4 asf4(uint4 u) {
    return make_float4(__uint_as_float(u.x), __uint_as_float(u.y),
                       __uint_as_float(u.z), __uint_as_float(u.w));
}

// ---------------- degree (both relations) ----------------
__global__ void deg2_kernel(const int* __restrict__ dstA, const int* __restrict__ dstB,
                            int* __restrict__ degA, int* __restrict__ degB, int E) {
    int e = blockIdx.x * blockDim.x + threadIdx.x;
    const int* dst = blockIdx.y ? dstB : dstA;
    int* deg = blockIdx.y ? degB : degA;
    if (e < E) atomicAdd(&deg[dst[e]], 1);
}

// ---------------- exclusive scan (3-kernel, both relations) ----------------
__global__ __launch_bounds__(256)
void scan1m(const int* __restrict__ degA, const int* __restrict__ degB,
            int* __restrict__ rpA, int* __restrict__ rpB,
            int* __restrict__ partA, int* __restrict__ partB, int N) {
    const int* deg = blockIdx.y ? degB : degA;
    int* rp = blockIdx.y ? rpB : rpA;
    int* partials = blockIdx.y ? partB : partA;
    int tid = threadIdx.x;
    int i = blockIdx.x * 256 + tid;
    int v = (i < N) ? deg[i] : 0;
    int lane = tid & 63, wid = tid >> 6;
    int x = v;
#pragma unroll
    for (int off = 1; off < 64; off <<= 1) {
        int y = __shfl_up(x, off, 64);
        if (lane >= off) x += y;
    }
    __shared__ int wsum[5];
    if (lane == 63) wsum[wid] = x;
    __syncthreads();
    if (tid == 0) {
        int a = wsum[0], b = wsum[1], c = wsum[2], d = wsum[3];
        wsum[0] = 0; wsum[1] = a; wsum[2] = a + b; wsum[3] = a + b + c;
        wsum[4] = a + b + c + d;
    }
    __syncthreads();
    if (i < N) rp[i] = wsum[wid] + x - v;
    if (tid == 0) partials[blockIdx.x] = wsum[4];
}

__global__ __launch_bounds__(1024)
void scan2m(int* __restrict__ partA, int* __restrict__ partB, int B) {
    int* partials = blockIdx.x ? partB : partA;
    __shared__ int buf[1024];
    int t = threadIdx.x;
    int v = (t < B) ? partials[t] : 0;
    buf[t] = v;
    __syncthreads();
    for (int off = 1; off < 1024; off <<= 1) {
        int add = (t >= off) ? buf[t - off] : 0;
        __syncthreads();
        buf[t] += add;
        __syncthreads();
    }
    if (t < B) partials[t] = buf[t] - v;
}

__global__ __launch_bounds__(256)
void scan3m(int* __restrict__ rpA, int* __restrict__ rpB,
            const int* __restrict__ partA, const int* __restrict__ partB, int N, int E) {
    int* rp = blockIdx.y ? rpB : rpA;
    const int* partials = blockIdx.y ? partB : partA;
    int i = blockIdx.x * 256 + threadIdx.x;
    if (i < N) rp[i] += partials[blockIdx.x];
    if (i == 0) rp[N] = E;
}

// ---------------- CSR fill (both relations) + first-8 pack ----------------
__global__ void fill2_csr(const int* __restrict__ srcA, const int* __restrict__ dstA,
                          const int* __restrict__ rpA, int* __restrict__ curA,
                          int* __restrict__ colA, int* __restrict__ colpA,
                          const int* __restrict__ srcB, const int* __restrict__ dstB,
                          const int* __restrict__ rpB, int* __restrict__ curB,
                          int* __restrict__ colB, int* __restrict__ colpB, int E) {
    int e = blockIdx.x * blockDim.x + threadIdx.x;
    if (e >= E) return;
    const int* src = blockIdx.y ? srcB : srcA;
    const int* dst = blockIdx.y ? dstB : dstA;
    const int* rp  = blockIdx.y ? rpB : rpA;
    int* cursor = blockIdx.y ? curB : curA;
    int* col    = blockIdx.y ? colB : colA;
    int* colp   = blockIdx.y ? colpB : colpA;
    int d = dst[e];
    int s = src[e];
    int idx = atomicAdd(&cursor[d], 1);
    col[rp[d] + idx] = s;
    if (idx < 8) colp[(size_t)d * 8 + idx] = s;
}

// ---------------- weight prep: transpose + bf16 h/l split ----------------
// WT layout per config g: [col 0..127][kv 0..255] (kv<128 self, >=128 neigh)
__global__ __launch_bounds__(256)
void prep_weights(const float* __restrict__ s0, const float* __restrict__ n0,
                  const float* __restrict__ s1, const float* __restrict__ n1,
                  const float* __restrict__ s2, const float* __restrict__ n2,
                  const float* __restrict__ s3, const float* __restrict__ n3,
                  ushort* __restrict__ WTH, ushort* __restrict__ WTL) {
    int g = blockIdx.y;
    int t = blockIdx.x * 256 + threadIdx.x;   // 0..4095
    int c = t & 127;
    int oct = t >> 7;                          // 0..31 (8 kv each)
    const float* self  = g == 0 ? s0 : g == 1 ? s1 : g == 2 ? s2 : s3;
    const float* neigh = g == 0 ? n0 : g == 1 ? n1 : g == 2 ? n2 : n3;
    uint hd[4], ld_[4];
#pragma unroll
    for (int p = 0; p < 4; ++p) {
        uint hpair = 0, lpair = 0;
#pragma unroll
        for (int q = 0; q < 2; ++q) {
            int kv = oct * 8 + p * 2 + q;
            const float* Wsrc = kv < 128 ? self : neigh;
            float f = Wsrc[(size_t)(kv & 127) * 128 + c];
            uint u = __float_as_uint(f);
            uint h = u >> 16;
            float r = f - __uint_as_float(u & 0xffff0000u);
            uint v = __float_as_uint(r);
            uint l = (v + 0x7fffu + ((v >> 16) & 1u)) >> 16;
            hpair |= h << (16 * q);
            lpair |= l << (16 * q);
        }
        hd[p] = hpair; ld_[p] = lpair;
    }
    size_t base = ((size_t)g * 128 + c) * 256 + oct * 8;
    *(uint4*)(WTH + base) = make_uint4(hd[0], hd[1], hd[2], hd[3]);
    *(uint4*)(WTL + base) = make_uint4(ld_[0], ld_[1], ld_[2], ld_[3]);
}

// ---------------- FUSED gather-mean + dual GEMM: 64-row tile, BK=64, colp8 ----------------
// 512 threads = 8 waves of 32x32. 4 phases of 2 K-steps: ph0-1 A1 streamed, ph2-3 Agg resident.
// 8 barriers/block (vs 16). LDS 80KB -> 2 blocks/CU.
// LDS: AggH[0,16K) AggL[16K,32K) Astep[32K,48K) Wh[48K,64K) Wl[64K,80K).
#define AGGH 0
#define AGGL 16384
#define ASTEP 32768
#define WHO 49152
#define WLO 65536

template<int FP32IN, int SPLIT, int LRELU>
__device__ __forceinline__ void fused_body(const char* A1, const char* XN,
        const int* rp, const int* col, const int* colp,
        const ushort* WTh, const ushort* WTl, const float* bias, void* outp,
        int bid, char* smem) {
    const int t = threadIdx.x;
    const int row0 = bid * 64;
    const int li = t & 15;

    // ---- gather phase: 64 nodes, 16 lanes/node, 2 passes; first-8 via colp8
#pragma unroll
    for (int p = 0; p < 2; ++p) {
        int nl = p * 32 + (t >> 4);            // 0..63
        int node = row0 + nl;
        int beg = rp[node], end = rp[node + 1];
        int dg = end - beg;
        int4 c4 = *(const int4*)(colp + (size_t)node * 8);
        int s0 = dg > 0 ? c4.x : 0;
        int s1 = dg > 1 ? c4.y : 0;
        int s2 = dg > 2 ? c4.z : 0;
        int s3 = dg > 3 ? c4.w : 0;
        float w0 = dg > 0 ? 1.f : 0.f;
        float w1 = dg > 1 ? 1.f : 0.f;
        float w2 = dg > 2 ? 1.f : 0.f;
        float w3 = dg > 3 ? 1.f : 0.f;
        float a[8];
#pragma unroll
        for (int j = 0; j < 8; ++j) a[j] = 0.f;
        const int lo = FP32IN ? li * 32 : li * 16;
        const int d2 = FP32IN ? 16 : 256;
        {
            const char* p0 = XN + (size_t)s0 * 512 + lo;
            const char* p1 = XN + (size_t)s1 * 512 + lo;
            const char* p2 = XN + (size_t)s2 * 512 + lo;
            const char* p3 = XN + (size_t)s3 * 512 + lo;
            uint4 H0 = *(const uint4*)p0, L0 = *(const uint4*)(p0 + d2);
            uint4 H1 = *(const uint4*)p1, L1 = *(const uint4*)(p1 + d2);
            uint4 H2 = *(const uint4*)p2, L2 = *(const uint4*)(p2 + d2);
            uint4 H3 = *(const uint4*)p3, L3 = *(const uint4*)(p3 + d2);
#pragma unroll
            for (int q = 0; q < 4; ++q) {
                uint4 Hq = q == 0 ? H0 : q == 1 ? H1 : q == 2 ? H2 : H3;
                uint4 Lq = q == 0 ? L0 : q == 1 ? L1 : q == 2 ? L2 : L3;
                float wq = q == 0 ? w0 : q == 1 ? w1 : q == 2 ? w2 : w3;
                if (FP32IN) {
                    float4 X = asf4(Hq), Y = asf4(Lq);
                    a[0] = fmaf(X.x, wq, a[0]); a[1] = fmaf(X.y, wq, a[1]);
                    a[2] = fmaf(X.z, wq, a[2]); a[3] = fmaf(X.w, wq, a[3]);
                    a[4] = fmaf(Y.x, wq, a[4]); a[5] = fmaf(Y.y, wq, a[5]);
                    a[6] = fmaf(Y.z, wq, a[6]); a[7] = fmaf(Y.w, wq, a[7]);
                } else {
                    const ushort* hu = (const ushort*)&Hq;
                    const ushort* lu = (const ushort*)&Lq;
#pragma unroll
                    for (int j = 0; j < 8; ++j) {
                        float v = __uint_as_float((uint)hu[j] << 16)
                                + __uint_as_float((uint)lu[j] << 16);
                        a[j] = fmaf(v, wq, a[j]);
                    }
                }
            }
        }
        if (dg > 4) {   // second quad: 4 parallel loads (covers deg<=8, ~99.9%)
            int4 c4b = *(const int4*)(colp + (size_t)node * 8 + 4);
            int s4 = c4b.x;
            int s5 = dg > 5 ? c4b.y : s4;
            int s6 = dg > 6 ? c4b.z : s4;
            int s7 = dg > 7 ? c4b.w : s4;
            float w5 = dg > 5 ? 1.f : 0.f;
            float w6 = dg > 6 ? 1.f : 0.f;
            float w7 = dg > 7 ? 1.f : 0.f;
            const char* p4 = XN + (size_t)s4 * 512 + lo;
            const char* p5 = XN + (size_t)s5 * 512 + lo;
            const char* p6 = XN + (size_t)s6 * 512 + lo;
            const char* p7 = XN + (size_t)s7 * 512 + lo;
            uint4 H4 = *(const uint4*)p4, L4 = *(const uint4*)(p4 + d2);
            uint4 H5 = *(const uint4*)p5, L5 = *(const uint4*)(p5 + d2);
            uint4 H6 = *(const uint4*)p6, L6 = *(const uint4*)(p6 + d2);
            uint4 H7 = *(const uint4*)p7, L7 = *(const uint4*)(p7 + d2);
#pragma unroll
            for (int q = 0; q < 4; ++q) {
                uint4 Hq = q == 0 ? H4 : q == 1 ? H5 : q == 2 ? H6 : H7;
                uint4 Lq = q == 0 ? L4 : q == 1 ? L5 : q == 2 ? L6 : L7;
                float wq = q == 0 ? 1.f : q == 1 ? w5 : q == 2 ? w6 : w7;
                if (FP32IN) {
                    float4 X = asf4(Hq), Y = asf4(Lq);
                    a[0] = fmaf(X.x, wq, a[0]); a[1] = fmaf(X.y, wq, a[1]);
                    a[2] = fmaf(X.z, wq, a[2]); a[3] = fmaf(X.w, wq, a[3]);
                    a[4] = fmaf(Y.x, wq, a[4]); a[5] = fmaf(Y.y, wq, a[5]);
                    a[6] = fmaf(Y.z, wq, a[6]); a[7] = fmaf(Y.w, wq, a[7]);
                } else {
                    const ushort* hu = (const ushort*)&Hq;
                    const ushort* lu = (const ushort*)&Lq;
#pragma unroll
                    for (int j = 0; j < 8; ++j) {
                        float v = __uint_as_float((uint)hu[j] << 16)
                                + __uint_as_float((uint)lu[j] << 16);
                        a[j] = fmaf(v, wq, a[j]);
                    }
                }
            }
            for (int e = beg + 8; e < end; ++e) {   // deg>8 only (~0.1%)
                const char* pp = XN + (size_t)col[e] * 512 + lo;
                uint4 H = *(const uint4*)pp, L = *(const uint4*)(pp + d2);
                if (FP32IN) {
                    float4 X = asf4(H), Y = asf4(L);
                    a[0] += X.x; a[1] += X.y; a[2] += X.z; a[3] += X.w;
                    a[4] += Y.x; a[5] += Y.y; a[6] += Y.z; a[7] += Y.w;
                } else {
                    const ushort* hu = (const ushort*)&H;
                    const ushort* lu = (const ushort*)&L;
#pragma unroll
                    for (int j = 0; j < 8; ++j)
                        a[j] += __uint_as_float((uint)hu[j] << 16)
                              + __uint_as_float((uint)lu[j] << 16);
                }
            }
        }
        float inv = 1.f / (float)(dg > 0 ? dg : 1);
        uint h[4], l[4];
        split2(a[0] * inv, a[1] * inv, h[0], l[0]);
        split2(a[2] * inv, a[3] * inv, h[1], l[1]);
        split2(a[4] * inv, a[5] * inv, h[2], l[2]);
        split2(a[6] * inv, a[7] * inv, h[3], l[3]);
        int chunk = li ^ (nl & 3) ^ (((nl >> 2) & 3) << 2);   // involution over 16 chunks
        *(uint4*)(smem + AGGH + nl * 256 + chunk * 16) = make_uint4(h[0], h[1], h[2], h[3]);
        *(uint4*)(smem + AGGL + nl * 256 + chunk * 16) = make_uint4(l[0], l[1], l[2], l[3]);
    }

    // ---- MFMA setup: 8 waves, 32 rows x 32 cols each
    const int w = t >> 6, lane = t & 63;
    const int fr = lane & 15, hi = lane >> 4;
    const int mrow0 = (w & 1) * 32, ncol0 = (w >> 1) * 32;

    f4 acc[2][2];
    {
        float bv[2];
#pragma unroll
        for (int n = 0; n < 2; ++n) bv[n] = bias[ncol0 + n * 16 + fr];
#pragma unroll
        for (int m = 0; m < 2; ++m)
#pragma unroll
            for (int n = 0; n < 2; ++n) acc[m][n] = (f4){bv[n], bv[n], bv[n], bv[n]};
    }

    // ---- K-loop: 4 phases of BK=64 (2 K-steps each)
    for (int ph = 0; ph < 4; ++ph) {
        // stage A (phases 0-1 only: A1 streamed; phases 2-3 use resident Agg)
        if (ph < 2) {
            if (FP32IN) {
#pragma unroll
                for (int it = 0; it < 2; ++it) {
                    int j = it * 512 + t;              // 0..1023: 64 rows x 16 chunks
                    int row = j >> 4, c = j & 15;
                    gl16(A1 + (size_t)(row0 + row) * 512 + ph * 256
                             + ((c ^ ((row & 7) << 1)) * 16),
                         smem + ASTEP + j * 16);
                }
            } else {
                int j = t;                              // 0..511: 64 rows x 8 chunks
                int row = j >> 3, c2 = j & 7;
                size_t so = (size_t)(row0 + row) * 512 + ph * 128 + ((c2 ^ (row & 7)) * 16);
                gl16(A1 + so, smem + ASTEP + j * 16);            // H
                gl16(A1 + so + 256, smem + ASTEP + 8192 + j * 16); // L
            }
        }
        // stage W: 128 cols x 8 chunks per plane
#pragma unroll
        for (int it = 0; it < 2; ++it) {
            int j = it * 512 + t;                       // 0..1023
            int col_ = j >> 3, c2 = j & 7;
            size_t so = (size_t)col_ * 512 + ph * 128 + ((c2 ^ (col_ & 7)) * 16);
            gl16((const char*)WTh + so, smem + WHO + j * 16);
            gl16((const char*)WTl + so, smem + WLO + j * 16);
        }
        __syncthreads();

        // compute both K-steps of this phase
#pragma unroll
        for (int j = 0; j < 2; ++j) {
            s8b ah[2], al[2], wh[2], wl[2];
            if (ph < 2) {
                if (FP32IN) {
#pragma unroll
                    for (int m = 0; m < 2; ++m) {
                        int r = mrow0 + m * 16 + fr;
                        int c0 = ((j * 8 + hi * 2) ^ ((r & 7) << 1));
                        f4 x0 = *(const f4*)(smem + ASTEP + r * 256 + c0 * 16);
                        f4 x1 = *(const f4*)(smem + ASTEP + r * 256 + c0 * 16 + 16);
                        U4 H, L;
                        split2(x0[0], x0[1], H.u[0], L.u[0]);
                        split2(x0[2], x0[3], H.u[1], L.u[1]);
                        split2(x1[0], x1[1], H.u[2], L.u[2]);
                        split2(x1[2], x1[3], H.u[3], L.u[3]);
                        ah[m] = H.v; al[m] = L.v;
                    }
                } else {
#pragma unroll
                    for (int m = 0; m < 2; ++m) {
                        int r = mrow0 + m * 16 + fr;
                        int chunk = (j * 4 + hi) ^ (r & 7);
                        ah[m] = *(const s8b*)(smem + ASTEP + r * 128 + chunk * 16);
                        al[m] = *(const s8b*)(smem + ASTEP + 8192 + r * 128 + chunk * 16);
                    }
                }
            } else {
                int kk = (ph - 2) * 2 + j;
#pragma unroll
                for (int m = 0; m < 2; ++m) {
                    int r = mrow0 + m * 16 + fr;
                    int chunk = (kk * 4 + hi) ^ (r & 3) ^ (((r >> 2) & 3) << 2);
                    ah[m] = *(const s8b*)(smem + AGGH + r * 256 + chunk * 16);
                    al[m] = *(const s8b*)(smem + AGGL + r * 256 + chunk * 16);
                }
            }
#pragma unroll
            for (int n = 0; n < 2; ++n) {
                int c = ncol0 + n * 16 + fr;
                int chunk = (j * 4 + hi) ^ (c & 7);
                wh[n] = *(const s8b*)(smem + WHO + c * 128 + chunk * 16);
                wl[n] = *(const s8b*)(smem + WLO + c * 128 + chunk * 16);
            }
#pragma unroll
            for (int n = 0; n < 2; ++n)
#pragma unroll
                for (int m = 0; m < 2; ++m) {
                    acc[m][n] = __builtin_amdgcn_mfma_f32_16x16x32_bf16(ah[m], wh[n], acc[m][n], 0, 0, 0);
                    acc[m][n] = __builtin_amdgcn_mfma_f32_16x16x32_bf16(al[m], wh[n], acc[m][n], 0, 0, 0);
                    acc[m][n] = __builtin_amdgcn_mfma_f32_16x16x32_bf16(ah[m], wl[n], acc[m][n], 0, 0, 0);
                }
        }
        __syncthreads();
    }

    // ---- epilogue: LDS transpose (64 x 132 fp32 = 33.8KB, reuses Agg region)
    float* T = (float*)smem;
#pragma unroll
    for (int m = 0; m < 2; ++m)
#pragma unroll
        for (int n = 0; n < 2; ++n)
#pragma unroll
            for (int r = 0; r < 4; ++r)
                T[(mrow0 + m * 16 + hi * 4 + r) * 132 + ncol0 + n * 16 + fr] = acc[m][n][r];
    __syncthreads();
    {
        int row = t >> 3, q = t & 7;            // 8 lanes per row
        int gr = row0 + row;
        if (SPLIT) {
            char* ob = (char*)outp + (size_t)gr * 512;
#pragma unroll
            for (int i = 0; i < 2; ++i) {
                const float* p = T + row * 132 + (q * 2 + i) * 8;
                f4 x0 = *(const f4*)p;
                f4 x1 = *(const f4*)(p + 4);
                float e[8] = {x0[0], x0[1], x0[2], x0[3], x1[0], x1[1], x1[2], x1[3]};
                if (LRELU) {
#pragma unroll
                    for (int jj = 0; jj < 8; ++jj) e[jj] = e[jj] > 0.f ? e[jj] : 0.01f * e[jj];
                }
                uint h[4], l[4];
#pragma unroll
                for (int jj = 0; jj < 4; ++jj) split2(e[2 * jj], e[2 * jj + 1], h[jj], l[jj]);
                *(uint4*)(ob + (q * 2 + i) * 16) = make_uint4(h[0], h[1], h[2], h[3]);
                *(uint4*)(ob + 256 + (q * 2 + i) * 16) = make_uint4(l[0], l[1], l[2], l[3]);
            }
        } else {
            float* ob = (float*)outp + (size_t)gr * 128;
#pragma unroll
            for (int i = 0; i < 4; ++i) {
                f4 x = *(const f4*)(T + row * 132 + q * 16 + i * 4);
                float e0 = x[0], e1 = x[1], e2 = x[2], e3 = x[3];
                if (LRELU) {
                    e0 = e0 > 0.f ? e0 : 0.01f * e0;
                    e1 = e1 > 0.f ? e1 : 0.01f * e1;
                    e2 = e2 > 0.f ? e2 : 0.01f * e2;
                    e3 = e3 > 0.f ? e3 : 0.01f * e3;
                }
                *(float4*)(ob + q * 16 + i * 4) = make_float4(e0, e1, e2, e3);
            }
        }
    }
}

template<int FP32IN, int SPLIT, int LRELU>
__global__ __launch_bounds__(512, 4)
void fused2k(const void* A1a, const void* XNa, const int* rpA, const int* colA,
             const int* colpA, const ushort* WTha, const ushort* WTla,
             const float* ba, void* outa,
             const void* A1b, const void* XNb, const int* rpB, const int* colB,
             const int* colpB, const ushort* WThb, const ushort* WTlb,
             const float* bb, void* outb, int blocksA) {
    __shared__ __align__(16) char smem[81920];
    bool isA = (int)blockIdx.x < blocksA;
    int bid = isA ? blockIdx.x : blockIdx.x - blocksA;
    if (isA)
        fused_body<FP32IN, SPLIT, LRELU>((const char*)A1a, (const char*)XNa, rpA, colA,
                                         colpA, WTha, WTla, ba, outa, bid, smem);
    else
        fused_body<FP32IN, SPLIT, LRELU>((const char*)A1b, (const char*)XNb, rpB, colB,
                                         colpB, WThb, WTlb, bb, outb, bid, smem);
}

extern "C" void kernel_launch(void* const* d_in, const int* in_sizes, int n_in,
                              void* d_out, int out_size, void* d_ws, size_t ws_size,
                              hipStream_t stream) {
    const float* x_user     = (const float*)d_in[0];
    const float* x_item     = (const float*)d_in[1];
    const float* w1_self_uc = (const float*)d_in[2];
    const float* w1_neigh_uc= (const float*)d_in[3];
    const float* b1_uc      = (const float*)d_in[4];
    const float* w1_self_iu = (const float*)d_in[5];
    const float* w1_neigh_iu= (const float*)d_in[6];
    const float* b1_iu      = (const float*)d_in[7];
    const float* w2_self_uc = (const float*)d_in[8];
    const float* w2_neigh_uc= (const float*)d_in[9];
    const float* b2_uc      = (const float*)d_in[10];
    const float* w2_self_iu = (const float*)d_in[11];
    const float* w2_neigh_iu= (const float*)d_in[12];
    const float* b2_iu      = (const float*)d_in[13];
    const int* src_uc = (const int*)d_in[14];
    const int* dst_uc = (const int*)d_in[15];
    const int* src_iu = (const int*)d_in[16];
    const int* dst_iu = (const int*)d_in[17];

    const int NU = in_sizes[0] / D_;
    const int NI = in_sizes[1] / D_;
    const int E  = in_sizes[14];

    float* f_user = (float*)d_out;
    float* f_item = (float*)d_out + (size_t)NU * 128;

    // workspace layout: h1 (hl form) lives in ws; d_out written only by layer 2
    char* ws = (char*)d_ws;
    const size_t FEAT_BYTES = (size_t)200000 * 512;      // 102.4 MB (hl rows)
    char* h1_item  = ws;          ws += FEAT_BYTES;
    char* h1_user  = ws;          ws += FEAT_BYTES;
    ushort* WTH    = (ushort*)ws; ws += (size_t)4 * 128 * 256 * sizeof(ushort);
    ushort* WTL    = (ushort*)ws; ws += (size_t)4 * 128 * 256 * sizeof(ushort);
    int* colp_uc   = (int*)ws;    ws += (size_t)200000 * 8 * sizeof(int);  // 6.4MB
    int* colp_iu   = (int*)ws;    ws += (size_t)200000 * 8 * sizeof(int);
    int* rp_uc     = (int*)ws;    ws += (size_t)(NI + 1) * sizeof(int);
    int* rp_iu     = (int*)ws;    ws += (size_t)(NU + 1) * sizeof(int);
    int* col_uc    = (int*)ws;    ws += (size_t)E * sizeof(int);
    int* col_iu    = (int*)ws;    ws += (size_t)E * sizeof(int);
    int* deg_uc    = (int*)ws;    ws += (size_t)200000 * sizeof(int);
    int* deg_iu    = (int*)ws;    ws += (size_t)200000 * sizeof(int);
    int* cur_uc    = (int*)ws;    ws += (size_t)200000 * sizeof(int);
    int* cur_iu    = (int*)ws;    ws += (size_t)200000 * sizeof(int);
    int* partA     = (int*)ws;    ws += (size_t)1024 * sizeof(int);
    int* partB     = (int*)ws;    ws += (size_t)1024 * sizeof(int);

    const int TPB = 256;
    const int eBlocks  = (E + TPB - 1) / TPB;
    const int sBlocks  = (200000 + 255) / 256;
    const int mBlocksI = (NI + 63) / 64;
    const int mBlocksU = (NU + 63) / 64;
    const size_t WSTRIDE = (size_t)128 * 256;  // g0=l1_uc g1=l1_iu g2=l2_uc g3=l2_iu

    hipMemsetAsync(deg_uc, 0, (size_t)4 * 200000 * sizeof(int), stream); // deg+cursor both rel

    prep_weights<<<dim3(16, 4), 256, 0, stream>>>(
        w1_self_uc, w1_neigh_uc, w1_self_iu, w1_neigh_iu,
        w2_self_uc, w2_neigh_uc, w2_self_iu, w2_neigh_iu, WTH, WTL);

    deg2_kernel<<<dim3(eBlocks, 2), TPB, 0, stream>>>(dst_uc, dst_iu, deg_uc, deg_iu, E);
    scan1m<<<dim3(sBlocks, 2), 256, 0, stream>>>(deg_uc, deg_iu, rp_uc, rp_iu, partA, partB, 200000);
    scan2m<<<2, 1024, 0, stream>>>(partA, partB, sBlocks);
    scan3m<<<dim3(sBlocks, 2), 256, 0, stream>>>(rp_uc, rp_iu, partA, partB, 200000, E);
    fill2_csr<<<dim3(eBlocks, 2), TPB, 0, stream>>>(src_uc, dst_uc, rp_uc, cur_uc, col_uc, colp_uc,
                                                    src_iu, dst_iu, rp_iu, cur_iu, col_iu, colp_iu, E);

    // ---- layer 1 (fused): item side gathers x_user via uc-CSR; user side gathers x_item
    fused2k<1, 1, 1><<<mBlocksI + mBlocksU, 512, 0, stream>>>(
        x_item, x_user, rp_uc, col_uc, colp_uc, WTH + 0 * WSTRIDE, WTL + 0 * WSTRIDE,
        b1_uc, h1_item,
        x_user, x_item, rp_iu, col_iu, colp_iu, WTH + 1 * WSTRIDE, WTL + 1 * WSTRIDE,
        b1_iu, h1_user, mBlocksI);

    // ---- layer 2 (fused): reads h1 from ws, writes fp32 d_out (no aliasing)
    fused2k<0, 0, 0><<<mBlocksI + mBlocksU, 512, 0, stream>>>(
        h1_item, h1_user, rp_uc, col_uc, colp_uc, WTH + 2 * WSTRIDE, WTL + 2 * WSTRIDE,
        b2_uc, f_item,
        h1_user, h1_item, rp_iu, col_iu, colp_iu, WTH + 3 * WSTRIDE, WTL + 3 * WSTRIDE,
        b2_iu, f_user, mBlocksI);
}